// Round 7
// baseline (83.209 us; speedup 1.0000x reference)
//
#include <hip/hip_runtime.h>

typedef float v2f __attribute__((ext_vector_type(2)));

#define KS 7
#define NG 16
#define PAD 3
#define NB 4
#define NC 64
#define NH 128
#define NW 128
#define HW (NH*NW)
#define NR 16
#define CG 4            // NC/NG
#define KK 49           // KS*KS

#define BTH 16          // block tile rows
#define BTW 32          // block tile cols
#define HTH 22          // BTH + 2*PAD
#define HTW 38          // BTW + 2*PAD

// ---------------- Kernel A: red[b][pix][r] = relu(w_reduce @ x + b_reduce) ----
__global__ __launch_bounds__(256)
void red_kernel(const float* __restrict__ x,
                const float* __restrict__ w_reduce,
                const float* __restrict__ b_reduce,
                float* __restrict__ red) {
    __shared__ float wT[NC][4];            // this rq's 4 rows, transposed
    const int t  = threadIdx.x;
    const int rq = blockIdx.y;             // 0..3
    {
        int e = t >> 6, c = t & 63;        // 256 threads cover 64x4
        wT[c][e] = w_reduce[(rq * 4 + e) * NC + c];
    }
    __syncthreads();

    const int p   = blockIdx.x * 256 + t;  // 0..65535
    const int b   = p >> 14;
    const int pix = p & 16383;

    float a0 = b_reduce[rq * 4 + 0];
    float a1 = b_reduce[rq * 4 + 1];
    float a2 = b_reduce[rq * 4 + 2];
    float a3 = b_reduce[rq * 4 + 3];

    const float* xp = x + (size_t)b * (NC * HW) + pix;
    #pragma unroll 16
    for (int c = 0; c < NC; ++c) {
        float xv = xp[(size_t)c * HW];     // coalesced across lanes
        float4 ww = *(const float4*)&wT[c][0];   // broadcast
        a0 = fmaf(ww.x, xv, a0);
        a1 = fmaf(ww.y, xv, a1);
        a2 = fmaf(ww.z, xv, a2);
        a3 = fmaf(ww.w, xv, a3);
    }
    float4 o = make_float4(fmaxf(a0, 0.f), fmaxf(a1, 0.f),
                           fmaxf(a2, 0.f), fmaxf(a3, 0.f));
    *(float4*)(red + (size_t)p * NR + rq * 4) = o;
}

// ---------------- Kernel B: fused span->exp->gather -------------------------
// Block = one group, 16x32 tile, 4 waves (8-col slices, 2 px/lane).
// KEY CHANGE vs R6: weights are loaded as per-lane GLOBAL loads (VMEM /
// vmcnt) instead of LDS or s_load (lgkmcnt). The LDS pipe then carries ONLY
// the 98 gather ds_read_b128 per wave, and weight latency pipelines on the
// independent vmcnt counter. The opaque vzero defeats uniformity analysis
// so the compiler cannot turn these back into s_loads.
__global__ __launch_bounds__(256, 2)
void invol_kernel(const float* __restrict__ x,
                  const float* __restrict__ w_span,
                  const float* __restrict__ b_span,
                  const float* __restrict__ red,
                  float* __restrict__ out) {
    __shared__ float4 xs[HTH * HTW];       // 836 * 16B = 13376 B

    const int t    = threadIdx.x;
    const int lane = t & 63;
    const int wv   = __builtin_amdgcn_readfirstlane(t >> 6);   // 0..3
    const int ph = lane >> 3, pw = lane & 7;
    const int h0 = (blockIdx.x >> 2) * BTH;    // 8 tile-rows
    const int w0 = (blockIdx.x & 3) * BTW;     // 4 tile-cols
    const int g  = blockIdx.y;
    const int b  = blockIdx.z;

    // ---- stage 22x38 float4 halo (4 group-channels per position) ----
    const float* xb = x + (size_t)(b * NC + g * CG) * HW;
    #pragma unroll
    for (int it = 0; it < 4; ++it) {
        int idx = t + it * 256;            // need < 836
        if (idx < HTH * HTW) {
            int hh = idx / HTW;
            int ww = idx - hh * HTW;
            int gh = h0 + hh - PAD;
            int gw = w0 + ww - PAD;
            float4 v = make_float4(0.f, 0.f, 0.f, 0.f);
            if ((unsigned)gh < NH && (unsigned)gw < NW) {
                const float* p = xb + gh * NW + gw;
                v.x = p[0];
                v.y = p[HW];
                v.z = p[2 * HW];
                v.w = p[3 * HW];
            }
            xs[idx] = v;
        }
    }
    __syncthreads();

    // ---- reduced features for both pixels, packed pixel-pair into v2f ----
    const int col  = wv * 8 + pw;          // 0..31
    const int pix1 = (h0 + ph) * NW + (w0 + col);
    const float4* rp1 = (const float4*)(red + ((size_t)b * HW + pix1) * NR);
    const float4* rp2 = (const float4*)(red + ((size_t)b * HW + pix1 + 8 * NW) * NR);
    v2f rv[NR];
    #pragma unroll
    for (int q = 0; q < 4; ++q) {
        float4 u1 = rp1[q], u2 = rp2[q];
        rv[q * 4 + 0] = (v2f){u1.x, u2.x};
        rv[q * 4 + 1] = (v2f){u1.y, u2.y};
        rv[q * 4 + 2] = (v2f){u1.z, u2.z};
        rv[q * 4 + 3] = (v2f){u1.w, u2.w};
    }

    // ---- opaque zero: forces per-lane (VMEM) weight loads, not s_load ----
    int vzero;
    asm volatile("v_mov_b32 %0, 0" : "=v"(vzero));
    const float4* wg4 = (const float4*)(w_span + (size_t)g * (KK * NR)) + vzero;
    const float*  bgv = b_span + (size_t)g * KK + vzero;

    // ---- fused per-tap: logit-pair -> exp -> weighted gather ----
    const int lb = ph * HTW + col;         // lane's base position in xs
    v2f esum = {0.f, 0.f};
    float a10 = 0.f, a11 = 0.f, a12 = 0.f, a13 = 0.f;
    float a20 = 0.f, a21 = 0.f, a22 = 0.f, a23 = 0.f;
    #pragma unroll
    for (int i = 0; i < KS; ++i) {
        #pragma unroll
        for (int j = 0; j < KS; ++j) {
            const int k = i * KS + j;
            float4 wa  = wg4[k * 4 + 0];   // VMEM broadcast (L1-hot)
            float4 wb_ = wg4[k * 4 + 1];
            float4 wc  = wg4[k * 4 + 2];
            float4 wd  = wg4[k * 4 + 3];
            float  bk  = bgv[k];
            v2f p0 = {bk, bk}, p1 = {0.f, 0.f}, p2 = {0.f, 0.f}, p3 = {0.f, 0.f};
            p0 += rv[0]  * wa.x;  p1 += rv[1]  * wa.y;
            p2 += rv[2]  * wa.z;  p3 += rv[3]  * wa.w;
            p0 += rv[4]  * wb_.x; p1 += rv[5]  * wb_.y;
            p2 += rv[6]  * wb_.z; p3 += rv[7]  * wb_.w;
            p0 += rv[8]  * wc.x;  p1 += rv[9]  * wc.y;
            p2 += rv[10] * wc.z;  p3 += rv[11] * wc.w;
            p0 += rv[12] * wd.x;  p1 += rv[13] * wd.y;
            p2 += rv[14] * wd.z;  p3 += rv[15] * wd.w;
            v2f pl = (p0 + p1) + (p2 + p3);
            float e1 = __expf(pl.x);       // logits O(1): no max-sub needed
            float e2 = __expf(pl.y);
            esum += (v2f){e1, e2};
            float4 v1 = xs[lb + i * HTW + j];              // DS, imm offsets
            float4 v2 = xs[lb + (8 + i) * HTW + j];
            a10 = fmaf(e1, v1.x, a10); a11 = fmaf(e1, v1.y, a11);
            a12 = fmaf(e1, v1.z, a12); a13 = fmaf(e1, v1.w, a13);
            a20 = fmaf(e2, v2.x, a20); a21 = fmaf(e2, v2.y, a21);
            a22 = fmaf(e2, v2.z, a22); a23 = fmaf(e2, v2.w, a23);
        }
    }
    float inv1 = 1.0f / esum.x;
    float inv2 = 1.0f / esum.y;

    const int h1 = h0 + ph, w = w0 + col;
    size_t ob1 = ((size_t)(b * NC + g * CG) * NH + h1) * NW + w;
    size_t ob2 = ob1 + 8 * NW;
    out[ob1]          = a10 * inv1;
    out[ob1 + HW]     = a11 * inv1;
    out[ob1 + 2 * HW] = a12 * inv1;
    out[ob1 + 3 * HW] = a13 * inv1;
    out[ob2]          = a20 * inv2;
    out[ob2 + HW]     = a21 * inv2;
    out[ob2 + 2 * HW] = a22 * inv2;
    out[ob2 + 3 * HW] = a23 * inv2;
}

extern "C" void kernel_launch(void* const* d_in, const int* in_sizes, int n_in,
                              void* d_out, int out_size, void* d_ws, size_t ws_size,
                              hipStream_t stream) {
    const float* x        = (const float*)d_in[0];
    const float* w_reduce = (const float*)d_in[1];
    const float* b_reduce = (const float*)d_in[2];
    const float* w_span   = (const float*)d_in[3];
    const float* b_span   = (const float*)d_in[4];
    float* out = (float*)d_out;
    float* red = (float*)d_ws;               // 4 MB (B*H*W*16 fp32)

    red_kernel<<<dim3(NB * HW / 256, 4), 256, 0, stream>>>(x, w_reduce, b_reduce, red);

    dim3 gridB(32, NG, NB);                  // (16x32 tiles, groups, batch) = 2048
    invol_kernel<<<gridB, 256, 0, stream>>>(x, w_span, b_span, red, out);
}

// Round 8
// 68.682 us; speedup vs baseline: 1.2115x; 1.2115x over previous
//
#include <hip/hip_runtime.h>

typedef float v2f __attribute__((ext_vector_type(2)));

#define KS 7
#define NG 16
#define PAD 3
#define NB 4
#define NC 64
#define NH 128
#define NW 128
#define HW (NH*NW)
#define NR 16
#define CG 4            // NC/NG
#define KK 49           // KS*KS
#define LOG2E 1.44269504088896f

#define BTH 16          // block tile rows
#define BTW 32          // block tile cols
#define HTH 22          // BTH + 2*PAD
#define HTW 38          // BTW + 2*PAD

// ---------------- Kernel A: red[b][pix][r] = relu(w_reduce @ x + b_reduce) ----
__global__ __launch_bounds__(256)
void red_kernel(const float* __restrict__ x,
                const float* __restrict__ w_reduce,
                const float* __restrict__ b_reduce,
                float* __restrict__ red) {
    __shared__ float wT[NC][4];            // this rq's 4 rows, transposed
    const int t  = threadIdx.x;
    const int rq = blockIdx.y;             // 0..3
    {
        int e = t >> 6, c = t & 63;        // 256 threads cover 64x4
        wT[c][e] = w_reduce[(rq * 4 + e) * NC + c];
    }
    __syncthreads();

    const int p   = blockIdx.x * 256 + t;  // 0..65535
    const int b   = p >> 14;
    const int pix = p & 16383;

    float a0 = b_reduce[rq * 4 + 0];
    float a1 = b_reduce[rq * 4 + 1];
    float a2 = b_reduce[rq * 4 + 2];
    float a3 = b_reduce[rq * 4 + 3];

    const float* xp = x + (size_t)b * (NC * HW) + pix;
    #pragma unroll 16
    for (int c = 0; c < NC; ++c) {
        float xv = xp[(size_t)c * HW];     // coalesced across lanes
        float4 ww = *(const float4*)&wT[c][0];   // broadcast
        a0 = fmaf(ww.x, xv, a0);
        a1 = fmaf(ww.y, xv, a1);
        a2 = fmaf(ww.z, xv, a2);
        a3 = fmaf(ww.w, xv, a3);
    }
    float4 o = make_float4(fmaxf(a0, 0.f), fmaxf(a1, 0.f),
                           fmaxf(a2, 0.f), fmaxf(a3, 0.f));
    *(float4*)(red + (size_t)p * NR + rq * 4) = o;
}

// ---------------- Kernel B: fused span->exp->gather, chunked s_load weights ---
// Block = one group (g = blockIdx.y, truly uniform), 16x32 tile, 4 waves
// (8-col slices, 2 px/lane). Weights ride the SCALAR pipe (s_load): zero DS
// cost. Tap loop is chunked x4: per chunk, the 8 gather ds_read_b128 are
// issued FIRST, then the 5 uniform weight loads, then the math — so the one
// lgkmcnt drain per chunk lands with both streams already in flight.
__global__ __launch_bounds__(256, 4)
void invol_kernel(const float* __restrict__ x,
                  const float* __restrict__ w_span,
                  const float* __restrict__ b_span,
                  const float* __restrict__ red,
                  float* __restrict__ out) {
    __shared__ float4 xs[HTH * HTW];       // 836 * 16B = 13376 B

    const int t    = threadIdx.x;
    const int lane = t & 63;
    const int wv   = __builtin_amdgcn_readfirstlane(t >> 6);   // 0..3
    const int ph = lane >> 3, pw = lane & 7;
    const int h0 = (blockIdx.x >> 2) * BTH;    // 8 tile-rows
    const int w0 = (blockIdx.x & 3) * BTW;     // 4 tile-cols
    const int g  = blockIdx.y;                 // block-uniform
    const int b  = blockIdx.z;

    // ---- stage 22x38 float4 halo (4 group-channels per position) ----
    const float* xb = x + (size_t)(b * NC + g * CG) * HW;
    #pragma unroll
    for (int it = 0; it < 4; ++it) {
        int idx = t + it * 256;            // need < 836
        if (idx < HTH * HTW) {
            int hh = idx / HTW;
            int ww = idx - hh * HTW;
            int gh = h0 + hh - PAD;
            int gw = w0 + ww - PAD;
            float4 v = make_float4(0.f, 0.f, 0.f, 0.f);
            if ((unsigned)gh < NH && (unsigned)gw < NW) {
                const float* p = xb + gh * NW + gw;
                v.x = p[0];
                v.y = p[HW];
                v.z = p[2 * HW];
                v.w = p[3 * HW];
            }
            xs[idx] = v;
        }
    }
    __syncthreads();

    // ---- reduced features, pixel-pair packed, pre-scaled by log2(e) ----
    const int col  = wv * 8 + pw;          // 0..31
    const int pix1 = (h0 + ph) * NW + (w0 + col);
    const float4* rp1 = (const float4*)(red + ((size_t)b * HW + pix1) * NR);
    const float4* rp2 = (const float4*)(red + ((size_t)b * HW + pix1 + 8 * NW) * NR);
    v2f rv[NR];
    #pragma unroll
    for (int q = 0; q < 4; ++q) {
        float4 u1 = rp1[q], u2 = rp2[q];
        rv[q * 4 + 0] = (v2f){u1.x, u2.x} * LOG2E;
        rv[q * 4 + 1] = (v2f){u1.y, u2.y} * LOG2E;
        rv[q * 4 + 2] = (v2f){u1.z, u2.z} * LOG2E;
        rv[q * 4 + 3] = (v2f){u1.w, u2.w} * LOG2E;
    }

    const float4* wg4 = (const float4*)(w_span + (size_t)g * (KK * NR)); // s_load
    const float*  bg  = b_span + (size_t)g * KK;                          // s_load

    const int lb = ph * HTW + col;         // lane's base position in xs
    v2f esum = {0.f, 0.f};
    float a10 = 0.f, a11 = 0.f, a12 = 0.f, a13 = 0.f;
    float a20 = 0.f, a21 = 0.f, a22 = 0.f, a23 = 0.f;

    // ---- chunked tap loop: 12 chunks of 4 + final single tap ----
    #pragma unroll
    for (int c = 0; c < 13; ++c) {
        const int kbase = c * 4;
        const int ntap  = (c < 12) ? 4 : 1;

        // 1) gather reads for the whole chunk (DS, issued first)
        float4 v1[4], v2[4];
        #pragma unroll
        for (int u = 0; u < 4; ++u) {
            if (u < ntap) {
                const int k = kbase + u;
                const int i = k / KS, j = k - i * KS;
                v1[u] = xs[lb + i * HTW + j];
                v2[u] = xs[lb + (8 + i) * HTW + j];
            }
        }

        // 2) uniform weight/bias loads for the chunk (scalar pipe)
        float4 wr[4][4];
        #pragma unroll
        for (int u = 0; u < 4; ++u) {
            if (u < ntap) {
                const int k = kbase + u;
                wr[u][0] = wg4[k * 4 + 0];
                wr[u][1] = wg4[k * 4 + 1];
                wr[u][2] = wg4[k * 4 + 2];
                wr[u][3] = wg4[k * 4 + 3];
            }
        }
        float bq[4];
        #pragma unroll
        for (int u = 0; u < 4; ++u)
            if (u < ntap) bq[u] = bg[kbase + u];

        // 3) math
        #pragma unroll
        for (int u = 0; u < 4; ++u) {
            if (u < ntap) {
                float4 wa = wr[u][0], wb_ = wr[u][1], wc = wr[u][2], wd = wr[u][3];
                v2f p0 = {0.f, 0.f}, p1 = {0.f, 0.f}, p2 = {0.f, 0.f}, p3 = {0.f, 0.f};
                p0 += rv[0]  * wa.x;  p1 += rv[1]  * wa.y;
                p2 += rv[2]  * wa.z;  p3 += rv[3]  * wa.w;
                p0 += rv[4]  * wb_.x; p1 += rv[5]  * wb_.y;
                p2 += rv[6]  * wb_.z; p3 += rv[7]  * wb_.w;
                p0 += rv[8]  * wc.x;  p1 += rv[9]  * wc.y;
                p2 += rv[10] * wc.z;  p3 += rv[11] * wc.w;
                p0 += rv[12] * wd.x;  p1 += rv[13] * wd.y;
                p2 += rv[14] * wd.z;  p3 += rv[15] * wd.w;
                v2f pl = (p0 + p1) + (p2 + p3);
                float bk2 = bq[u] * LOG2E;           // uniform (SALU/mad)
                float e1 = exp2f(pl.x + bk2);        // bare v_exp_f32
                float e2 = exp2f(pl.y + bk2);
                esum += (v2f){e1, e2};
                a10 = fmaf(e1, v1[u].x, a10); a11 = fmaf(e1, v1[u].y, a11);
                a12 = fmaf(e1, v1[u].z, a12); a13 = fmaf(e1, v1[u].w, a13);
                a20 = fmaf(e2, v2[u].x, a20); a21 = fmaf(e2, v2[u].y, a21);
                a22 = fmaf(e2, v2[u].z, a22); a23 = fmaf(e2, v2[u].w, a23);
            }
        }
    }
    float inv1 = 1.0f / esum.x;
    float inv2 = 1.0f / esum.y;

    const int h1 = h0 + ph, w = w0 + col;
    size_t ob1 = ((size_t)(b * NC + g * CG) * NH + h1) * NW + w;
    size_t ob2 = ob1 + 8 * NW;
    out[ob1]          = a10 * inv1;
    out[ob1 + HW]     = a11 * inv1;
    out[ob1 + 2 * HW] = a12 * inv1;
    out[ob1 + 3 * HW] = a13 * inv1;
    out[ob2]          = a20 * inv2;
    out[ob2 + HW]     = a21 * inv2;
    out[ob2 + 2 * HW] = a22 * inv2;
    out[ob2 + 3 * HW] = a23 * inv2;
}

extern "C" void kernel_launch(void* const* d_in, const int* in_sizes, int n_in,
                              void* d_out, int out_size, void* d_ws, size_t ws_size,
                              hipStream_t stream) {
    const float* x        = (const float*)d_in[0];
    const float* w_reduce = (const float*)d_in[1];
    const float* b_reduce = (const float*)d_in[2];
    const float* w_span   = (const float*)d_in[3];
    const float* b_span   = (const float*)d_in[4];
    float* out = (float*)d_out;
    float* red = (float*)d_ws;               // 4 MB (B*H*W*16 fp32)

    red_kernel<<<dim3(NB * HW / 256, 4), 256, 0, stream>>>(x, w_reduce, b_reduce, red);

    dim3 gridB(32, NG, NB);                  // (16x32 tiles, groups, batch) = 2048
    invol_kernel<<<gridB, 256, 0, stream>>>(x, w_span, b_span, red, out);
}

// Round 9
// 55.446 us; speedup vs baseline: 1.5007x; 1.2387x over previous
//
#include <hip/hip_runtime.h>

typedef float  f32x4  __attribute__((ext_vector_type(4)));
typedef short  bf16x8 __attribute__((ext_vector_type(8)));

#define KS 7
#define NG 16
#define PAD 3
#define NB 4
#define NC 64
#define NH 128
#define NW 128
#define HW (NH*NW)
#define NR 16
#define CG 4
#define KK 49
#define L2E 1.44269504088896f
#define PADB -100000.0f
#define TS 16           // 16x16 pixel tile per wave
#define HT 22           // TS + 2*PAD

__device__ __forceinline__ unsigned short bf16rn(float f) {
    unsigned u = __float_as_uint(f);
    u += 0x7FFFu + ((u >> 16) & 1u);
    return (unsigned short)(u >> 16);
}
__device__ __forceinline__ float bf16tof(unsigned short h) {
    return __uint_as_float(((unsigned)h) << 16);
}

// ---- Kernel A: redpk[b*HW+px][32] = [bf16_hi(relu(conv)*log2e) x16 | bf16_lo x16]
__global__ __launch_bounds__(256)
void red_kernel(const float* __restrict__ x,
                const float* __restrict__ w_reduce,
                const float* __restrict__ b_reduce,
                unsigned short* __restrict__ redpk) {
    __shared__ float wT[NC][4];
    const int t  = threadIdx.x;
    const int rq = blockIdx.y;                 // 0..3: which 4 r's
    { int e = t >> 6, c = t & 63; wT[c][e] = w_reduce[(rq*4+e)*NC + c]; }
    __syncthreads();

    const int pth = blockIdx.x*256 + t;        // 0..65535 = b*16384+pix
    const int b   = pth >> 14;
    const int pix = pth & 16383;

    float aa[4];
    #pragma unroll
    for (int i = 0; i < 4; ++i) aa[i] = b_reduce[rq*4+i];

    const float* xp = x + (size_t)b*(NC*HW) + pix;
    #pragma unroll 16
    for (int c = 0; c < NC; ++c) {
        float xv = xp[(size_t)c*HW];           // coalesced
        float4 ww = *(const float4*)&wT[c][0]; // broadcast
        aa[0] = fmaf(ww.x, xv, aa[0]);
        aa[1] = fmaf(ww.y, xv, aa[1]);
        aa[2] = fmaf(ww.z, xv, aa[2]);
        aa[3] = fmaf(ww.w, xv, aa[3]);
    }

    unsigned short hv[4], lv[4];
    #pragma unroll
    for (int i = 0; i < 4; ++i) {
        float sv = fmaxf(aa[i], 0.f) * L2E;    // fold log2(e) into red
        unsigned short h = bf16rn(sv);
        hv[i] = h;
        lv[i] = bf16rn(sv - bf16tof(h));
    }
    unsigned short* rp = redpk + ((size_t)pth << 5);   // 32 ushorts per px
    *(ushort4*)(rp + rq*4)      = make_ushort4(hv[0],hv[1],hv[2],hv[3]);
    *(ushort4*)(rp + 16 + rq*4) = make_ushort4(lv[0],lv[1],lv[2],lv[3]);
}

// ---- Kernel B: MFMA span conv -> exp2 -> gather ------------------------------
// Block = 4 waves = 4 groups, one 16x16 spatial tile. Per wave:
//   A-frags: w_span split bf16 hi/lo, resident in VGPRs (loaded once).
//   Loop over 16 pixel rows: B-frag = redpk row (global b128), 8 MFMAs
//   (4 tap-tiles x 2 precision terms), exp2 on C regs, 13 ds_read_b128
//   gather, shfl_xor combine over the 4 tap lane-groups, q==0 stores.
__global__ __launch_bounds__(256, 4)
void invol_kernel(const float* __restrict__ x,
                  const float* __restrict__ w_span,
                  const float* __restrict__ b_span,
                  const unsigned short* __restrict__ redpk,
                  float* __restrict__ out) {
    __shared__ float4 xs[4][HT][HT];           // 30976 B

    const int t    = threadIdx.x;
    const int lane = t & 63;
    const int wv   = __builtin_amdgcn_readfirstlane(t >> 6);
    const int p    = lane & 15;                // pixel col (MFMA n / C col)
    const int q    = lane >> 4;                // k-group / C row group
    const int h0   = (blockIdx.x >> 3) * TS;   // 8x8 tiles of 16x16
    const int w0   = (blockIdx.x & 7) * TS;
    const int g    = blockIdx.y * 4 + wv;
    const int b    = blockIdx.z;

    // ---- stage 22x22 float4 halo (this wave's 4 group-channels) ----
    const float* xb = x + (size_t)(b*NC + g*CG)*HW;
    #pragma unroll
    for (int it = 0; it < 8; ++it) {
        int idx = lane + it*64;
        if (idx < HT*HT) {
            int hh = idx / HT, ww = idx - hh*HT;
            int gh = h0 + hh - PAD, gw = w0 + ww - PAD;
            float4 v = make_float4(0.f,0.f,0.f,0.f);
            if ((unsigned)gh < NH && (unsigned)gw < NW) {
                const float* pp = xb + gh*NW + gw;
                v.x = pp[0]; v.y = pp[HW]; v.z = pp[2*HW]; v.w = pp[3*HW];
            }
            xs[wv][hh][ww] = v;
        }
    }
    __syncthreads();

    // ---- A-fragments: taps padded to 64 (4 tiles of 16). lane m = p. ----
    // elem i covers k=(q-group dependent); k<16 -> w_hi, k>=16 -> w_lo.
    // Loads use (q&1)*8 so (A,B) share the same (q,i)->r mapping.
    const float* wg = w_span + (size_t)g*(KK*NR);
    bf16x8 A1[4];
    #pragma unroll
    for (int tt = 0; tt < 4; ++tt) {
        int tap = tt*16 + p; if (tap > 48) tap = 48;     // avoid OOB, e=0 anyway
        const float4* wr = (const float4*)(wg + tap*NR + (q & 1)*8);
        float4 u0 = wr[0], u1 = wr[1];
        float w8[8] = {u0.x,u0.y,u0.z,u0.w,u1.x,u1.y,u1.z,u1.w};
        bf16x8 a;
        #pragma unroll
        for (int i = 0; i < 8; ++i) {
            unsigned short h = bf16rn(w8[i]);
            unsigned short l = bf16rn(w8[i] - bf16tof(h));
            a[i] = (short)(q < 2 ? h : l);               // q0/1: hi, q2/3: lo
        }
        A1[tt] = a;
    }

    // ---- bias init (pre-scaled by log2e; pads -> -1e5 => exp2 -> 0) ----
    const float* bg = b_span + g*KK;
    f32x4 bias[4];
    #pragma unroll
    for (int tt = 0; tt < 3; ++tt) {
        float4 bb = *(const float4*)(bg + tt*16 + q*4);  // taps tt*16+q*4+{0..3}
        bias[tt][0] = bb.x*L2E; bias[tt][1] = bb.y*L2E;
        bias[tt][2] = bb.z*L2E; bias[tt][3] = bb.w*L2E;
    }
    bias[3][0] = (q == 0) ? bg[48]*L2E : PADB;           // tap 48 only
    bias[3][1] = PADB; bias[3][2] = PADB; bias[3][3] = PADB;

    // ---- 13 gather pointers: taps tt*16+q*4+r (tiles 0-2) + tap48 ----
    const float4* gp[13];
    #pragma unroll
    for (int tt = 0; tt < 3; ++tt) {
        #pragma unroll
        for (int r = 0; r < 4; ++r) {
            int tap = tt*16 + q*4 + r;
            int i = tap / 7, j = tap - i*7;
            gp[tt*4+r] = &xs[wv][i][p + j];
        }
    }
    gp[12] = &xs[wv][6][p + 6];                          // tap 48 = (6,6)

    bf16x8 zz;
    #pragma unroll
    for (int i = 0; i < 8; ++i) zz[i] = 0;

    // ---- main loop over the 16 pixel rows ----
    const unsigned short* rb =
        redpk + (((size_t)b*HW + (size_t)h0*NW + w0 + p) << 5) + ((q & 1) << 3);
    bf16x8 B1 = *(const bf16x8*)rb;                       // r_hi slice
    bf16x8 B2 = *(const bf16x8*)(rb + 16);                // r_lo slice
    B2 = (q < 2) ? B2 : zz;                               // upper-k term: w_hi*r_lo only

    #pragma unroll
    for (int ph = 0; ph < TS; ++ph) {
        bf16x8 B1n = B1, B2n = B2;
        if (ph < TS-1) {                                  // prefetch next row
            const unsigned short* rn = rb + (size_t)(ph+1)*(NW*32);
            B1n = *(const bf16x8*)rn;
            bf16x8 l2 = *(const bf16x8*)(rn + 16);
            B2n = (q < 2) ? l2 : zz;
        }

        f32x4 ac[4];
        #pragma unroll
        for (int tt = 0; tt < 4; ++tt) {
            f32x4 c0 = __builtin_amdgcn_mfma_f32_16x16x32_bf16(A1[tt], B1, bias[tt], 0,0,0);
            ac[tt]   = __builtin_amdgcn_mfma_f32_16x16x32_bf16(A1[tt], B2, c0,      0,0,0);
        }

        float e[16];
        float sum = 0.f;
        #pragma unroll
        for (int tt = 0; tt < 4; ++tt) {
            #pragma unroll
            for (int r = 0; r < 4; ++r) {
                float ev = exp2f(ac[tt][r]);             // padded taps -> 0
                e[tt*4+r] = ev;
                sum += ev;
            }
        }
        sum += __shfl_xor(sum, 16);                      // reduce over q-groups
        sum += __shfl_xor(sum, 32);

        float g0 = 0.f, g1 = 0.f, g2 = 0.f, g3 = 0.f;
        #pragma unroll
        for (int k = 0; k < 12; ++k) {
            float4 v = gp[k][ph*HT];                     // ds_read_b128, imm offset
            float ev = e[k];
            g0 = fmaf(ev, v.x, g0); g1 = fmaf(ev, v.y, g1);
            g2 = fmaf(ev, v.z, g2); g3 = fmaf(ev, v.w, g3);
        }
        {
            float4 v = gp[12][ph*HT];                    // tap 48 (e=0 for q>0)
            float ev = e[12];
            g0 = fmaf(ev, v.x, g0); g1 = fmaf(ev, v.y, g1);
            g2 = fmaf(ev, v.z, g2); g3 = fmaf(ev, v.w, g3);
        }
        g0 += __shfl_xor(g0, 16); g0 += __shfl_xor(g0, 32);
        g1 += __shfl_xor(g1, 16); g1 += __shfl_xor(g1, 32);
        g2 += __shfl_xor(g2, 16); g2 += __shfl_xor(g2, 32);
        g3 += __shfl_xor(g3, 16); g3 += __shfl_xor(g3, 32);

        if (q == 0) {
            float inv = 1.0f / sum;
            const int h = h0 + ph, w = w0 + p;
            size_t ob = ((size_t)(b*NC + g*CG)*NH + h)*NW + w;
            out[ob]        = g0 * inv;
            out[ob + HW]   = g1 * inv;
            out[ob + 2*HW] = g2 * inv;
            out[ob + 3*HW] = g3 * inv;
        }
        B1 = B1n; B2 = B2n;
    }
}

extern "C" void kernel_launch(void* const* d_in, const int* in_sizes, int n_in,
                              void* d_out, int out_size, void* d_ws, size_t ws_size,
                              hipStream_t stream) {
    const float* x        = (const float*)d_in[0];
    const float* w_reduce = (const float*)d_in[1];
    const float* b_reduce = (const float*)d_in[2];
    const float* w_span   = (const float*)d_in[3];
    const float* b_span   = (const float*)d_in[4];
    float* out = (float*)d_out;
    unsigned short* redpk = (unsigned short*)d_ws;   // 4 MB: B*HW*32 ushorts

    red_kernel<<<dim3(NB*HW/256, 4), 256, 0, stream>>>(x, w_reduce, b_reduce, redpk);

    dim3 gridB(64, NG/4, NB);                        // 1024 blocks = 4/CU exactly
    invol_kernel<<<gridB, 256, 0, stream>>>(x, w_span, b_span, redpk, out);
}